// Round 10
// baseline (555.054 us; speedup 1.0000x reference)
//
#include <hip/hip_runtime.h>
#include <hip/hip_bf16.h>
#include <stdint.h>

#define N_NODES 50000
#define N_EDGES 800000
#define D_IN    128
#define H_DIM   256
#define BN_EPS  1e-5f
#define LN_EPS  1e-5f
#define NBLK_SCAN 196  // ceil(50000/256)
#define SLICE_ELEMS ((size_t)N_NODES * 32)  // ushort elems per 32-col slice
#define EDGE_CHUNK 3072  // LDS descriptor staging (32 nodes x max-degree ~45 << 3072)

typedef float v4f __attribute__((ext_vector_type(4)));
typedef short v8s __attribute__((ext_vector_type(8)));

__device__ __forceinline__ float bflo(unsigned u){ return __uint_as_float(u << 16); }
__device__ __forceinline__ float bfhi(unsigned u){ return __uint_as_float(u & 0xffff0000u); }
__device__ __forceinline__ unsigned short f2bf(float f){
  unsigned u = __float_as_uint(f);
  u += 0x7fffu + ((u >> 16) & 1u);
  return (unsigned short)(u >> 16);
}
__device__ __forceinline__ unsigned pack2(float a, float b){
  return (unsigned)f2bf(a) | ((unsigned)f2bf(b) << 16);
}
__device__ __forceinline__ float wred(float v){
  #pragma unroll
  for (int m = 1; m < 64; m <<= 1) v += __shfl_xor(v, m, 64);
  return v;
}

// in-block (256 threads) exclusive scan of one int per thread
__device__ __forceinline__ int block_excl_scan(int v){
  int t = threadIdx.x;
  int lane = t & 63, w = t >> 6;
  int inc = v;
  #pragma unroll
  for (int m = 1; m < 64; m <<= 1){
    int o = __shfl_up(inc, m, 64);
    if (lane >= m) inc += o;
  }
  __shared__ int wsum[4];
  if (lane == 63) wsum[w] = inc;
  __syncthreads();
  int base = 0;
  #pragma unroll
  for (int j = 0; j < 4; ++j) if (j < w) base += wsum[j];
  return base + inc - v;  // exclusive
}

// ---------------- degree / degree-sort / CSR ----------------
__global__ void deg_k(const int* ei, int* cnt){
  int e = blockIdx.x * 256 + threadIdx.x;
  if (e < N_EDGES) atomicAdd(&cnt[ei[N_EDGES + e]], 1);
}

__global__ __launch_bounds__(256) void hist_k(const int* cnt, int* dhist){
  __shared__ int lh[64];
  int t = threadIdx.x;
  if (t < 64) lh[t] = 0;
  __syncthreads();
  int i = blockIdx.x * 256 + t;
  if (i < N_NODES) atomicAdd(&lh[min(cnt[i], 63)], 1);
  __syncthreads();
  if (t < 64 && lh[t] > 0) atomicAdd(&dhist[t], lh[t]);
}

__global__ void dscan_k(const int* dhist, int* dcur){
  int t = threadIdx.x; // 64
  int v = dhist[t];
  int inc = v;
  #pragma unroll
  for (int m = 1; m < 64; m <<= 1){
    int o = __shfl_up(inc, m, 64);
    if (t >= m) inc += o;
  }
  dcur[t] = inc - v;  // exclusive prefix
}

// counting-sort: perm[rank] = node, rank[node] = rank; also accumulate
// per-scan-block degree sums (bsum) for the offs scan (blocksum folded in)
__global__ __launch_bounds__(256) void dperm_k(const int* cnt, int* dcur, int* perm, int* rank,
                                               int* bsum){
  __shared__ int lh[64], lb[64], lc[64];
  int t = threadIdx.x;
  if (t < 64){ lh[t] = 0; lc[t] = 0; }
  __syncthreads();
  int i = blockIdx.x * 256 + t;
  int b = -1, deg = 0;
  if (i < N_NODES){ deg = cnt[i]; b = min(deg, 63); atomicAdd(&lh[b], 1); }
  __syncthreads();
  if (t < 64 && lh[t] > 0) lb[t] = atomicAdd(&dcur[t], lh[t]);
  __syncthreads();
  if (i < N_NODES){
    int r = atomicAdd(&lc[b], 1);
    int pos = lb[b] + r;
    perm[pos] = i;
    rank[i] = pos;
    atomicAdd(&bsum[pos >> 8], deg);
  }
}

__global__ __launch_bounds__(256) void bscan_k(const int* bsum, int* bpre, int* offs){
  int t = threadIdx.x;
  int v = (t < NBLK_SCAN) ? bsum[t] : 0;
  int e = block_excl_scan(v);
  if (t < NBLK_SCAN) bpre[t] = e;
  if (t == 0) offs[N_NODES] = N_EDGES;
}

// offsets/cursors in sorted order + dinv (indexed by original node id)
__global__ __launch_bounds__(256) void cscan_k(const int* cnt, const int* perm, const int* bpre,
                                               int* offs, int* curs, float* dinv){
  int t = threadIdx.x;
  int i = blockIdx.x * 256 + t;
  int node = 0, v = 0;
  if (i < N_NODES){ node = perm[i]; v = cnt[node]; }
  int e = block_excl_scan(v) + bpre[blockIdx.x];
  if (i < N_NODES){
    offs[i] = e; curs[i] = e;
    dinv[node] = rsqrtf((float)v + 1.0f);
  }
}

// edge descriptor: low 16 bits = src node id (N<65536), high 16 bits = bf16 weight
// edge lists stored at the dst node's RANK position -> agg reads sequentially
__global__ void csr_k(const int* ei, const float* dinv, const int* rank, int* cursor, unsigned* edges){
  int e = blockIdx.x * 256 + threadIdx.x;
  if (e >= N_EDGES) return;
  int s = ei[e], d = ei[N_EDGES + e];
  int p = atomicAdd(&cursor[rank[d]], 1);
  edges[p] = (unsigned)s | ((unsigned)f2bf(dinv[s] * dinv[d]) << 16);
}

// ---------------- BN0 stats over y = x*fs + fb ----------------
__global__ __launch_bounds__(256) void bn0stats_k(const float* x, const float* fs, const float* fb,
                                                  float* S, float* Q){
  int t = threadIdx.x;
  int cl = t & 31, rg = t >> 5;
  int c = cl * 4;
  float4 fs4 = *(const float4*)(fs + c);
  float4 fb4 = *(const float4*)(fb + c);
  float s0=0,s1=0,s2=0,s3=0,q0=0,q1=0,q2=0,q3=0;
  for (int row = blockIdx.x * 8 + rg; row < N_NODES; row += gridDim.x * 8){
    float4 xv = *(const float4*)(x + (size_t)row * D_IN + c);
    float v0 = xv.x * fs4.x + fb4.x;
    float v1 = xv.y * fs4.y + fb4.y;
    float v2 = xv.z * fs4.z + fb4.z;
    float v3 = xv.w * fs4.w + fb4.w;
    s0 += v0; s1 += v1; s2 += v2; s3 += v3;
    q0 += v0*v0; q1 += v1*v1; q2 += v2*v2; q3 += v3*v3;
  }
  __shared__ float red[256][8];
  red[t][0]=s0; red[t][1]=s1; red[t][2]=s2; red[t][3]=s3;
  red[t][4]=q0; red[t][5]=q1; red[t][6]=q2; red[t][7]=q3;
  __syncthreads();
  if (t < 32){
    float a[8];
    #pragma unroll
    for (int i = 0; i < 8; ++i) a[i] = red[t][i];
    for (int j = 1; j < 8; ++j)
      #pragma unroll
      for (int i = 0; i < 8; ++i) a[i] += red[t + 32*j][i];
    #pragma unroll
    for (int i = 0; i < 4; ++i){ atomicAdd(&S[t*4+i], a[i]); atomicAdd(&Q[t*4+i], a[4+i]); }
  }
}

// prepx with BN0 finalization fused: per-thread recompute of affine from stats
__global__ __launch_bounds__(256) void prepx_k(const float* x, const float* S, const float* Q,
                                               const float* fs, const float* fb,
                                               const float* gg, const float* bb,
                                               unsigned short* xt){
  int i = blockIdx.x * 256 + threadIdx.x; // N*32 total
  int row = i >> 5; int c = (i & 31) * 4;
  float4 Sv = *(const float4*)(S + c);
  float4 Qv = *(const float4*)(Q + c);
  float4 fs4 = *(const float4*)(fs + c);
  float4 fb4 = *(const float4*)(fb + c);
  float4 gg4 = *(const float4*)(gg + c);
  float4 bb4 = *(const float4*)(bb + c);
  const float invN = 1.0f / N_NODES;
  float mu0 = Sv.x*invN, mu1 = Sv.y*invN, mu2 = Sv.z*invN, mu3 = Sv.w*invN;
  float r0 = rsqrtf(Qv.x*invN - mu0*mu0 + BN_EPS);
  float r1 = rsqrtf(Qv.y*invN - mu1*mu1 + BN_EPS);
  float r2 = rsqrtf(Qv.z*invN - mu2*mu2 + BN_EPS);
  float r3 = rsqrtf(Qv.w*invN - mu3*mu3 + BN_EPS);
  float a0 = gg4.x*r0*fs4.x, b0 = gg4.x*r0*(fb4.x - mu0) + bb4.x;
  float a1 = gg4.y*r1*fs4.y, b1 = gg4.y*r1*(fb4.y - mu1) + bb4.y;
  float a2 = gg4.z*r2*fs4.z, b2 = gg4.z*r2*(fb4.z - mu2) + bb4.z;
  float a3 = gg4.w*r3*fs4.w, b3 = gg4.w*r3*(fb4.w - mu3) + bb4.w;
  float4 xv = *(const float4*)(x + (size_t)row * D_IN + c);
  uint2 o;
  o.x = pack2(a0 * xv.x + b0, a1 * xv.y + b1);
  o.y = pack2(a2 * xv.z + b2, a3 * xv.w + b3);
  *(uint2*)(xt + (size_t)row * D_IN + c) = o;
}

__global__ void transpose2_k(const float* W1, const float* W2,
                             unsigned short* W1t, unsigned short* W2t){
  int i = blockIdx.x * 256 + threadIdx.x;
  if (i < D_IN * H_DIM){
    int r = i / H_DIM, c = i % H_DIM;
    W1t[c * D_IN + r] = f2bf(W1[i]);
  }
  if (i < H_DIM * H_DIM){
    int r = i / H_DIM, c = i % H_DIM;
    W2t[c * H_DIM + r] = f2bf(W2[i]);
  }
}

// ---------------- bf16 MFMA GEMM: 64x256 tile, C slice-major [8][N][32] ----------------
template<int K>
__global__ __launch_bounds__(256) void gemm_k(const unsigned short* A, const unsigned short* Bt,
                                              unsigned short* C, int M){
  __shared__ __align__(16) short smem[16896];
  short* As = smem;               // [64][40]
  short* Bs = smem + 64 * 40;     // [256][40]
  int t = threadIdx.x;
  int m0 = blockIdx.x * 64;
  int lane = t & 63;
  int w = t >> 6;                 // wave -> col block w*64
  int fr = lane & 15, quad = lane >> 4;
  v4f acc[4][4] = {};
  int sr = t >> 2;                // 0..63
  int sk = (t & 3) << 3;          // 0,8,16,24
  for (int k0 = 0; k0 < K; k0 += 32){
    __syncthreads();
    uint4 av = {0,0,0,0};
    int arow = m0 + sr;
    if (arow < M) av = *(const uint4*)(A + (size_t)arow * K + k0 + sk);
    *(uint4*)(&As[sr * 40 + sk]) = av;
    #pragma unroll
    for (int j = 0; j < 4; ++j){
      int brow = sr + 64 * j;
      uint4 bv = *(const uint4*)(Bt + (size_t)brow * K + k0 + sk);
      *(uint4*)(&Bs[brow * 40 + sk]) = bv;
    }
    __syncthreads();
    v8s af[4], bf[4];
    #pragma unroll
    for (int mi = 0; mi < 4; ++mi)
      af[mi] = *(const v8s*)(&As[(mi * 16 + fr) * 40 + quad * 8]);
    #pragma unroll
    for (int ni = 0; ni < 4; ++ni)
      bf[ni] = *(const v8s*)(&Bs[(w * 64 + ni * 16 + fr) * 40 + quad * 8]);
    #pragma unroll
    for (int mi = 0; mi < 4; ++mi)
      #pragma unroll
      for (int ni = 0; ni < 4; ++ni)
        acc[mi][ni] = __builtin_amdgcn_mfma_f32_16x16x32_bf16(af[mi], bf[ni], acc[mi][ni], 0, 0, 0);
  }
  __syncthreads();
  short* Cs = smem; // [64][264]
  #pragma unroll
  for (int mi = 0; mi < 4; ++mi)
    #pragma unroll
    for (int ni = 0; ni < 4; ++ni)
      #pragma unroll
      for (int r = 0; r < 4; ++r){
        int row = mi * 16 + quad * 4 + r;
        int col = w * 64 + ni * 16 + fr;
        Cs[row * 264 + col] = (short)f2bf(acc[mi][ni][r]);
      }
  __syncthreads();
  int orow = t >> 2;
  int grow = m0 + orow;
  if (grow < M){
    #pragma unroll
    for (int j = 0; j < 4; ++j){
      int oc = (t & 3) * 16 + 64 * j;
      v8s v0 = *(const v8s*)(&Cs[orow * 264 + oc]);
      v8s v1 = *(const v8s*)(&Cs[orow * 264 + oc + 8]);
      *(v8s*)(&C[(size_t)(oc >> 5) * SLICE_ELEMS + (size_t)grow * 32 + (oc & 31)]) = v0;
      int oc1 = oc + 8;
      *(v8s*)(&C[(size_t)(oc1 >> 5) * SLICE_ELEMS + (size_t)grow * 32 + (oc1 & 31)]) = v1;
    }
  }
}

// ---------------- edge aggregation: XCD-sliced, LDS-staged descriptors ----------------
// hs: slice-major hlin [8][N][32]; blockIdx.x & 7 = slice; idx = degree rank.
// Block's 32 nodes have a CONTIGUOUS edge window (rank-sequential CSR) -> stage it in LDS
// with coalesced loads; per-group desc reads become ds_reads (no global hop in the chain).
__global__ __launch_bounds__(256) void agg_k(const unsigned short* hs, const int* offsets,
                                             const unsigned* edges, const int* perm,
                                             const float* dinv, const float* bias,
                                             unsigned short* g){
  __shared__ unsigned eds[EDGE_CHUNK];
  int t = threadIdx.x;
  int lane = t & 63;
  int slice = blockIdx.x & 7;
  int l8 = lane & 7;
  int nb = (blockIdx.x >> 3) * 32;
  int idx = nb + (t >> 3);
  int lastn = min(nb + 32, N_NODES);
  int blk0 = offsets[nb];
  int blkN = offsets[lastn];
  int wcnt = min(blkN - blk0, EDGE_CHUNK);
  for (int i = t; i < wcnt; i += 256)
    eds[i] = edges[blk0 + i];
  __syncthreads();
  if (idx >= N_NODES) return;
  int node = perm[idx];
  const unsigned short* hb = hs + (size_t)slice * SLICE_ELEMS;
  float4 bb = *(const float4*)(bias + slice * 32 + l8 * 4);
  float di = dinv[node]; float dii = di * di;
  uint2 sv = *(const uint2*)(hb + (size_t)node * 32 + l8 * 4);
  float a0 = bb.x + dii * bflo(sv.x);
  float a1 = bb.y + dii * bfhi(sv.x);
  float a2 = bb.z + dii * bflo(sv.y);
  float a3 = bb.w + dii * bfhi(sv.y);
  int e  = offsets[idx];
  int e1 = offsets[idx + 1];
  // 8 edges per iteration: descs from LDS, 8 independent gathers in flight
  for (; e + 8 <= e1; e += 8){
    int r = e - blk0;
    unsigned d0, d1, d2, d3, d4, d5, d6, d7;
    if (r + 8 <= EDGE_CHUNK){
      d0 = eds[r];   d1 = eds[r+1]; d2 = eds[r+2]; d3 = eds[r+3];
      d4 = eds[r+4]; d5 = eds[r+5]; d6 = eds[r+6]; d7 = eds[r+7];
    } else {
      d0 = edges[e];   d1 = edges[e+1]; d2 = edges[e+2]; d3 = edges[e+3];
      d4 = edges[e+4]; d5 = edges[e+5]; d6 = edges[e+6]; d7 = edges[e+7];
    }
    uint2 v0 = *(const uint2*)(hb + (size_t)(d0 & 0xffffu) * 32 + l8 * 4);
    uint2 v1 = *(const uint2*)(hb + (size_t)(d1 & 0xffffu) * 32 + l8 * 4);
    uint2 v2 = *(const uint2*)(hb + (size_t)(d2 & 0xffffu) * 32 + l8 * 4);
    uint2 v3 = *(const uint2*)(hb + (size_t)(d3 & 0xffffu) * 32 + l8 * 4);
    uint2 v4 = *(const uint2*)(hb + (size_t)(d4 & 0xffffu) * 32 + l8 * 4);
    uint2 v5 = *(const uint2*)(hb + (size_t)(d5 & 0xffffu) * 32 + l8 * 4);
    uint2 v6 = *(const uint2*)(hb + (size_t)(d6 & 0xffffu) * 32 + l8 * 4);
    uint2 v7 = *(const uint2*)(hb + (size_t)(d7 & 0xffffu) * 32 + l8 * 4);
    float w0 = __uint_as_float(d0 & 0xffff0000u), w1 = __uint_as_float(d1 & 0xffff0000u);
    float w2 = __uint_as_float(d2 & 0xffff0000u), w3 = __uint_as_float(d3 & 0xffff0000u);
    float w4 = __uint_as_float(d4 & 0xffff0000u), w5 = __uint_as_float(d5 & 0xffff0000u);
    float w6 = __uint_as_float(d6 & 0xffff0000u), w7 = __uint_as_float(d7 & 0xffff0000u);
    a0 += w0*bflo(v0.x) + w1*bflo(v1.x) + w2*bflo(v2.x) + w3*bflo(v3.x)
        + w4*bflo(v4.x) + w5*bflo(v5.x) + w6*bflo(v6.x) + w7*bflo(v7.x);
    a1 += w0*bfhi(v0.x) + w1*bfhi(v1.x) + w2*bfhi(v2.x) + w3*bfhi(v3.x)
        + w4*bfhi(v4.x) + w5*bfhi(v5.x) + w6*bfhi(v6.x) + w7*bfhi(v7.x);
    a2 += w0*bflo(v0.y) + w1*bflo(v1.y) + w2*bflo(v2.y) + w3*bflo(v3.y)
        + w4*bflo(v4.y) + w5*bflo(v5.y) + w6*bflo(v6.y) + w7*bflo(v7.y);
    a3 += w0*bfhi(v0.y) + w1*bfhi(v1.y) + w2*bfhi(v2.y) + w3*bfhi(v3.y)
        + w4*bfhi(v4.y) + w5*bfhi(v5.y) + w6*bfhi(v6.y) + w7*bfhi(v7.y);
  }
  // tail
  for (; e < e1; ++e){
    int r = e - blk0;
    unsigned d = (r < EDGE_CHUNK) ? eds[r] : edges[e];
    uint2 v = *(const uint2*)(hb + (size_t)(d & 0xffffu) * 32 + l8 * 4);
    float wg = __uint_as_float(d & 0xffff0000u);
    a0 += wg * bflo(v.x); a1 += wg * bfhi(v.x);
    a2 += wg * bflo(v.y); a3 += wg * bfhi(v.y);
  }
  uint2 o;
  o.x = pack2(fmaxf(a0, 0.f), fmaxf(a1, 0.f));
  o.y = pack2(fmaxf(a2, 0.f), fmaxf(a3, 0.f));
  *(uint2*)(g + (size_t)node * H_DIM + slice * 32 + l8 * 4) = o;
}

// ---------------- column stats over g (bf16 [N,256]) ----------------
__global__ __launch_bounds__(256) void colstats_k(const unsigned short* g, float* S, float* Q){
  int t = threadIdx.x;
  int cl = t & 63, rg = t >> 6;
  int c = cl * 4;
  float s0=0,s1=0,s2=0,s3=0,q0=0,q1=0,q2=0,q3=0;
  for (int row = blockIdx.x * 4 + rg; row < N_NODES; row += gridDim.x * 4){
    uint2 u = *(const uint2*)(g + (size_t)row * H_DIM + c);
    float v0 = bflo(u.x), v1 = bfhi(u.x), v2 = bflo(u.y), v3 = bfhi(u.y);
    s0 += v0; s1 += v1; s2 += v2; s3 += v3;
    q0 += v0*v0; q1 += v1*v1; q2 += v2*v2; q3 += v3*v3;
  }
  __shared__ float red[256][8];
  red[t][0]=s0; red[t][1]=s1; red[t][2]=s2; red[t][3]=s3;
  red[t][4]=q0; red[t][5]=q1; red[t][6]=q2; red[t][7]=q3;
  __syncthreads();
  if (t < 64){
    float a[8];
    #pragma unroll
    for (int i = 0; i < 8; ++i) a[i] = red[t][i];
    for (int j = 1; j < 4; ++j)
      #pragma unroll
      for (int i = 0; i < 8; ++i) a[i] += red[t + 64*j][i];
    #pragma unroll
    for (int i = 0; i < 4; ++i){ atomicAdd(&S[t*4+i], a[i]); atomicAdd(&Q[t*4+i], a[4+i]); }
  }
}

// per-thread BN finalize from raw stats (S,Q) for this thread's 4 columns
__device__ __forceinline__ void bn_coeffs(const float* S, const float* Q,
                                          const float* gg, const float* bb, int c,
                                          float4& sc, float4& sh){
  float4 Sv = *(const float4*)(S + c);
  float4 Qv = *(const float4*)(Q + c);
  float4 g4 = *(const float4*)(gg + c);
  float4 b4 = *(const float4*)(bb + c);
  const float invN = 1.0f / N_NODES;
  float mu0 = Sv.x*invN, mu1 = Sv.y*invN, mu2 = Sv.z*invN, mu3 = Sv.w*invN;
  sc.x = g4.x * rsqrtf(Qv.x*invN - mu0*mu0 + BN_EPS);
  sc.y = g4.y * rsqrtf(Qv.y*invN - mu1*mu1 + BN_EPS);
  sc.z = g4.z * rsqrtf(Qv.z*invN - mu2*mu2 + BN_EPS);
  sc.w = g4.w * rsqrtf(Qv.w*invN - mu3*mu3 + BN_EPS);
  sh.x = b4.x - sc.x * mu0; sh.y = b4.y - sc.y * mu1;
  sh.z = b4.z - sc.z * mu2; sh.w = b4.w - sc.w * mu3;
}

// ---------------- BN + LN apply (layer 1): h1 = LN(BN(g)) ----------------
__global__ __launch_bounds__(256) void apply1_k(const unsigned short* g, const float* S, const float* Q,
                                                const float* bng, const float* bnb,
                                                const float* lng, const float* lnb, unsigned short* h1){
  int lane = threadIdx.x & 63;
  int row = blockIdx.x * 4 + (threadIdx.x >> 6);
  if (row >= N_NODES) return;
  int c = lane * 4;
  float4 s4, h4;
  bn_coeffs(S, Q, bng, bnb, c, s4, h4);
  uint2 u = *(const uint2*)(g + (size_t)row * H_DIM + c);
  float v0 = s4.x * bflo(u.x) + h4.x;
  float v1 = s4.y * bfhi(u.x) + h4.y;
  float v2 = s4.z * bflo(u.y) + h4.z;
  float v3 = s4.w * bfhi(u.y) + h4.w;
  float sum = wred(v0 + v1 + v2 + v3);
  float sq  = wred(v0*v0 + v1*v1 + v2*v2 + v3*v3);
  float mu = sum * (1.0f / H_DIM);
  float var = sq * (1.0f / H_DIM) - mu * mu;
  float rs = rsqrtf(var + LN_EPS);
  float4 g4 = *(const float4*)(lng + c);
  float4 b4 = *(const float4*)(lnb + c);
  float y0 = g4.x * (v0 - mu) * rs + b4.x;
  float y1 = g4.y * (v1 - mu) * rs + b4.y;
  float y2 = g4.z * (v2 - mu) * rs + b4.z;
  float y3 = g4.w * (v3 - mu) * rs + b4.w;
  uint2 o; o.x = pack2(y0, y1); o.y = pack2(y2, y3);
  *(uint2*)(h1 + (size_t)row * H_DIM + c) = o;
}

// ---------------- layer 2 apply + residual + output GEMM ----------------
__global__ __launch_bounds__(256) void apply2_k(const unsigned short* g, const float* S, const float* Q,
                                                const float* bng, const float* bnb,
                                                const float* lng, const float* lnb,
                                                const unsigned short* h1, const float* Wout,
                                                const float* bout, float* out){
  int lane = threadIdx.x & 63;
  int row = blockIdx.x * 4 + (threadIdx.x >> 6);
  if (row >= N_NODES) return;
  int c = lane * 4;
  float4 s4, h4;
  bn_coeffs(S, Q, bng, bnb, c, s4, h4);
  uint2 u = *(const uint2*)(g + (size_t)row * H_DIM + c);
  float v0 = s4.x * bflo(u.x) + h4.x;
  float v1 = s4.y * bfhi(u.x) + h4.y;
  float v2 = s4.z * bflo(u.y) + h4.z;
  float v3 = s4.w * bfhi(u.y) + h4.w;
  float sum = wred(v0 + v1 + v2 + v3);
  float sq  = wred(v0*v0 + v1*v1 + v2*v2 + v3*v3);
  float mu = sum * (1.0f / H_DIM);
  float var = sq * (1.0f / H_DIM) - mu * mu;
  float rs = rsqrtf(var + LN_EPS);
  float4 g4 = *(const float4*)(lng + c);
  float4 b4 = *(const float4*)(lnb + c);
  uint2 hr = *(const uint2*)(h1 + (size_t)row * H_DIM + c);
  float y0 = g4.x * (v0 - mu) * rs + b4.x + bflo(hr.x);
  float y1 = g4.y * (v1 - mu) * rs + b4.y + bfhi(hr.x);
  float y2 = g4.z * (v2 - mu) * rs + b4.z + bflo(hr.y);
  float y3 = g4.w * (v3 - mu) * rs + b4.w + bfhi(hr.y);
  float4 w0 = *(const float4*)(Wout + c * 2);
  float4 w1 = *(const float4*)(Wout + c * 2 + 4);
  float o0 = y0 * w0.x + y1 * w0.z + y2 * w1.x + y3 * w1.z;
  float o1 = y0 * w0.y + y1 * w0.w + y2 * w1.y + y3 * w1.w;
  o0 = wred(o0); o1 = wred(o1);
  if (lane == 0){
    out[(size_t)row * 2 + 0] = o0 + bout[0];
    out[(size_t)row * 2 + 1] = o1 + bout[1];
  }
}

extern "C" void kernel_launch(void* const* d_in, const int* in_sizes, int n_in,
                              void* d_out, int out_size, void* d_ws, size_t ws_size,
                              hipStream_t stream) {
  const float* x    = (const float*)d_in[0];
  const int*   ei   = (const int*)d_in[1];
  const float* fs   = (const float*)d_in[2];
  const float* fb   = (const float*)d_in[3];
  const float* bn0g = (const float*)d_in[4];
  const float* bn0b = (const float*)d_in[5];
  const float* W1   = (const float*)d_in[6];
  const float* b1   = (const float*)d_in[7];
  const float* bn1g = (const float*)d_in[8];
  const float* bn1b = (const float*)d_in[9];
  const float* ln1g = (const float*)d_in[10];
  const float* ln1b = (const float*)d_in[11];
  const float* W2   = (const float*)d_in[12];
  const float* b2   = (const float*)d_in[13];
  const float* bn2g = (const float*)d_in[14];
  const float* bn2b = (const float*)d_in[15];
  const float* ln2g = (const float*)d_in[16];
  const float* ln2b = (const float*)d_in[17];
  const float* Wout = (const float*)d_in[18];
  const float* bout = (const float*)d_in[19];
  float* out = (float*)d_out;

  char* w = (char*)d_ws;
  // zeroed region (one memset): cnt + stat sums + degree histogram + bsum
  int*   cnt   = (int*)(w + 0);            // 200000 B
  float* bn0S  = (float*)(w + 200000);     // 512
  float* bn0Q  = (float*)(w + 200512);     // 512
  float* S1    = (float*)(w + 201024);     // 1024
  float* Q1    = (float*)(w + 202048);     // 1024
  float* S2    = (float*)(w + 203072);     // 1024
  float* Q2    = (float*)(w + 204096);     // 1024 -> 205120
  int*   dhist = (int*)(w + 205120);       // 256  -> 205376
  int*   bsum  = (int*)(w + 205376);       // 1024 -> 206400
  const size_t ZERO_BYTES = 206400;
  int*   dcur  = (int*)(w + 206400);       // 256  -> 206656
  int*   bpre  = (int*)(w + 206656);       // 1024 -> 207680
  float* dinv  = (float*)(w + 207680);     // 200000 -> 407680
  int*   offs  = (int*)(w + 407680);       // 200004 -> pad 607744
  int*   curs  = (int*)(w + 607744);       // 200000 -> 807744
  int*   perm  = (int*)(w + 807744);       // 200000 -> 1007744
  int*   rank  = (int*)(w + 1007744);      // 200000 -> 1207744
  unsigned* edges = (unsigned*)(w + 1207744); // 3200000 -> 4407744 (16B aligned)
  unsigned short* xt   = (unsigned short*)(w + 4407744);   // 12.8 MB -> 17207744
  unsigned short* W1t  = (unsigned short*)(w + 17207744);  // 64 KB  -> 17273280
  unsigned short* W2t  = (unsigned short*)(w + 17273280);  // 128 KB -> 17404352
  unsigned short* hlin = (unsigned short*)(w + 17404352);  // 25.6 MB (slice-major [8][N][32])
  unsigned short* gbuf = (unsigned short*)(w + 43004352);  // 25.6 MB (row-major)
  unsigned short* h1   = (unsigned short*)(w + 68604352);  // 25.6 MB -> 94204352

  (void)in_sizes; (void)n_in; (void)out_size; (void)ws_size;

  hipMemsetAsync(d_ws, 0, ZERO_BYTES, stream);

  // graph preprocessing: degree -> degree-sort relabeling (blocksum folded) -> sorted CSR
  deg_k<<<(N_EDGES + 255) / 256, 256, 0, stream>>>(ei, cnt);
  hist_k<<<NBLK_SCAN, 256, 0, stream>>>(cnt, dhist);
  dscan_k<<<1, 64, 0, stream>>>(dhist, dcur);
  dperm_k<<<NBLK_SCAN, 256, 0, stream>>>(cnt, dcur, perm, rank, bsum);
  bscan_k<<<1, 256, 0, stream>>>(bsum, bpre, offs);
  cscan_k<<<NBLK_SCAN, 256, 0, stream>>>(cnt, perm, bpre, offs, curs, dinv);
  csr_k<<<(N_EDGES + 255) / 256, 256, 0, stream>>>(ei, dinv, rank, curs, edges);

  // input transform + BN0 folded into affine, cast to bf16 (finalize fused in prepx)
  bn0stats_k<<<128, 256, 0, stream>>>(x, fs, fb, bn0S, bn0Q);
  prepx_k<<<(N_NODES * 32) / 256, 256, 0, stream>>>(x, bn0S, bn0Q, fs, fb, bn0g, bn0b, xt);

  // weight transposes (bf16, K-inner), merged
  transpose2_k<<<(H_DIM * H_DIM + 255) / 256, 256, 0, stream>>>(W1, W2, W1t, W2t);

  int ggrid = (N_NODES + 63) / 64;
  int agg_blocks = ((N_NODES + 31) / 32) * 8;

  // ---- layer 1 ----
  gemm_k<D_IN><<<ggrid, 256, 0, stream>>>(xt, W1t, hlin, N_NODES);
  agg_k<<<agg_blocks, 256, 0, stream>>>(hlin, offs, edges, perm, dinv, b1, gbuf);
  colstats_k<<<104, 256, 0, stream>>>(gbuf, S1, Q1);
  apply1_k<<<(N_NODES + 3) / 4, 256, 0, stream>>>(gbuf, S1, Q1, bn1g, bn1b, ln1g, ln1b, h1);

  // ---- layer 2 ----
  gemm_k<H_DIM><<<ggrid, 256, 0, stream>>>(h1, W2t, hlin, N_NODES);
  agg_k<<<agg_blocks, 256, 0, stream>>>(hlin, offs, edges, perm, dinv, b2, gbuf);
  colstats_k<<<104, 256, 0, stream>>>(gbuf, S2, Q2);
  apply2_k<<<(N_NODES + 3) / 4, 256, 0, stream>>>(gbuf, S2, Q2, bn2g, bn2b, ln2g, ln2b, h1, Wout, bout, out);
}

// Round 11
// 480.660 us; speedup vs baseline: 1.1548x; 1.1548x over previous
//
#include <hip/hip_runtime.h>
#include <hip/hip_bf16.h>
#include <stdint.h>

#define N_NODES 50000
#define N_EDGES 800000
#define D_IN    128
#define H_DIM   256
#define BN_EPS  1e-5f
#define LN_EPS  1e-5f
#define NBLK_SCAN 196  // ceil(50000/256)
#define SLICE_ELEMS ((size_t)N_NODES * 32)  // ushort elems per 32-col slice
#define EDGE_CHUNK 3072  // LDS descriptor staging (32 nodes x max-degree ~45 << 3072)

typedef float v4f __attribute__((ext_vector_type(4)));
typedef short v8s __attribute__((ext_vector_type(8)));

__device__ __forceinline__ float bflo(unsigned u){ return __uint_as_float(u << 16); }
__device__ __forceinline__ float bfhi(unsigned u){ return __uint_as_float(u & 0xffff0000u); }
__device__ __forceinline__ unsigned short f2bf(float f){
  unsigned u = __float_as_uint(f);
  u += 0x7fffu + ((u >> 16) & 1u);
  return (unsigned short)(u >> 16);
}
__device__ __forceinline__ unsigned pack2(float a, float b){
  return (unsigned)f2bf(a) | ((unsigned)f2bf(b) << 16);
}
__device__ __forceinline__ float wred(float v){
  #pragma unroll
  for (int m = 1; m < 64; m <<= 1) v += __shfl_xor(v, m, 64);
  return v;
}

// in-block (256 threads) exclusive scan of one int per thread
__device__ __forceinline__ int block_excl_scan(int v){
  int t = threadIdx.x;
  int lane = t & 63, w = t >> 6;
  int inc = v;
  #pragma unroll
  for (int m = 1; m < 64; m <<= 1){
    int o = __shfl_up(inc, m, 64);
    if (lane >= m) inc += o;
  }
  __shared__ int wsum[4];
  if (lane == 63) wsum[w] = inc;
  __syncthreads();
  int base = 0;
  #pragma unroll
  for (int j = 0; j < 4; ++j) if (j < w) base += wsum[j];
  return base + inc - v;  // exclusive
}

// ---------------- degree / degree-sort / CSR ----------------
__global__ void deg_k(const int* ei, int* cnt){
  int e = blockIdx.x * 256 + threadIdx.x;
  if (e < N_EDGES) atomicAdd(&cnt[ei[N_EDGES + e]], 1);
}

__global__ __launch_bounds__(256) void hist_k(const int* cnt, int* dhist){
  __shared__ int lh[64];
  int t = threadIdx.x;
  if (t < 64) lh[t] = 0;
  __syncthreads();
  int i = blockIdx.x * 256 + t;
  if (i < N_NODES) atomicAdd(&lh[min(cnt[i], 63)], 1);
  __syncthreads();
  if (t < 64 && lh[t] > 0) atomicAdd(&dhist[t], lh[t]);
}

__global__ void dscan_k(const int* dhist, int* dcur){
  int t = threadIdx.x; // 64
  int v = dhist[t];
  int inc = v;
  #pragma unroll
  for (int m = 1; m < 64; m <<= 1){
    int o = __shfl_up(inc, m, 64);
    if (t >= m) inc += o;
  }
  dcur[t] = inc - v;  // exclusive prefix
}

// counting-sort: perm[rank] = node, rank[node] = rank (degree-ascending relabeling)
// NOTE: no global per-block-sum atomics here — that was a 78 µs atomic storm (round 10).
__global__ __launch_bounds__(256) void dperm_k(const int* cnt, int* dcur, int* perm, int* rank){
  __shared__ int lh[64], lb[64], lc[64];
  int t = threadIdx.x;
  if (t < 64){ lh[t] = 0; lc[t] = 0; }
  __syncthreads();
  int i = blockIdx.x * 256 + t;
  int b = -1;
  if (i < N_NODES){ b = min(cnt[i], 63); atomicAdd(&lh[b], 1); }
  __syncthreads();
  if (t < 64 && lh[t] > 0) lb[t] = atomicAdd(&dcur[t], lh[t]);
  __syncthreads();
  if (i < N_NODES){
    int r = atomicAdd(&lc[b], 1);
    int pos = lb[b] + r;
    perm[pos] = i;
    rank[i] = pos;
  }
}

// block sums over degree-sorted counts (separate kernel: wave-reduced, no atomic chains)
__global__ __launch_bounds__(256) void blocksum_k(const int* cnt, const int* perm, int* bsum){
  int i = blockIdx.x * 256 + threadIdx.x;
  int v = (i < N_NODES) ? cnt[perm[i]] : 0;
  #pragma unroll
  for (int m = 1; m < 64; m <<= 1) v += __shfl_xor(v, m, 64);
  __shared__ int ws[4];
  int t = threadIdx.x;
  if ((t & 63) == 0) ws[t >> 6] = v;
  __syncthreads();
  if (t == 0) bsum[blockIdx.x] = ws[0] + ws[1] + ws[2] + ws[3];
}

__global__ __launch_bounds__(256) void bscan_k(const int* bsum, int* bpre, int* offs){
  int t = threadIdx.x;
  int v = (t < NBLK_SCAN) ? bsum[t] : 0;
  int e = block_excl_scan(v);
  if (t < NBLK_SCAN) bpre[t] = e;
  if (t == 0) offs[N_NODES] = N_EDGES;
}

// offsets/cursors in sorted order + dinv (indexed by original node id)
__global__ __launch_bounds__(256) void cscan_k(const int* cnt, const int* perm, const int* bpre,
                                               int* offs, int* curs, float* dinv){
  int t = threadIdx.x;
  int i = blockIdx.x * 256 + t;
  int node = 0, v = 0;
  if (i < N_NODES){ node = perm[i]; v = cnt[node]; }
  int e = block_excl_scan(v) + bpre[blockIdx.x];
  if (i < N_NODES){
    offs[i] = e; curs[i] = e;
    dinv[node] = rsqrtf((float)v + 1.0f);
  }
}

// edge descriptor: low 16 bits = src node id (N<65536), high 16 bits = bf16 weight
// edge lists stored at the dst node's RANK position -> agg reads sequentially
__global__ void csr_k(const int* ei, const float* dinv, const int* rank, int* cursor, unsigned* edges){
  int e = blockIdx.x * 256 + threadIdx.x;
  if (e >= N_EDGES) return;
  int s = ei[e], d = ei[N_EDGES + e];
  int p = atomicAdd(&cursor[rank[d]], 1);
  edges[p] = (unsigned)s | ((unsigned)f2bf(dinv[s] * dinv[d]) << 16);
}

// ---------------- BN0 stats over y = x*fs + fb ----------------
__global__ __launch_bounds__(256) void bn0stats_k(const float* x, const float* fs, const float* fb,
                                                  float* S, float* Q){
  int t = threadIdx.x;
  int cl = t & 31, rg = t >> 5;
  int c = cl * 4;
  float4 fs4 = *(const float4*)(fs + c);
  float4 fb4 = *(const float4*)(fb + c);
  float s0=0,s1=0,s2=0,s3=0,q0=0,q1=0,q2=0,q3=0;
  for (int row = blockIdx.x * 8 + rg; row < N_NODES; row += gridDim.x * 8){
    float4 xv = *(const float4*)(x + (size_t)row * D_IN + c);
    float v0 = xv.x * fs4.x + fb4.x;
    float v1 = xv.y * fs4.y + fb4.y;
    float v2 = xv.z * fs4.z + fb4.z;
    float v3 = xv.w * fs4.w + fb4.w;
    s0 += v0; s1 += v1; s2 += v2; s3 += v3;
    q0 += v0*v0; q1 += v1*v1; q2 += v2*v2; q3 += v3*v3;
  }
  __shared__ float red[256][8];
  red[t][0]=s0; red[t][1]=s1; red[t][2]=s2; red[t][3]=s3;
  red[t][4]=q0; red[t][5]=q1; red[t][6]=q2; red[t][7]=q3;
  __syncthreads();
  if (t < 32){
    float a[8];
    #pragma unroll
    for (int i = 0; i < 8; ++i) a[i] = red[t][i];
    for (int j = 1; j < 8; ++j)
      #pragma unroll
      for (int i = 0; i < 8; ++i) a[i] += red[t + 32*j][i];
    #pragma unroll
    for (int i = 0; i < 4; ++i){ atomicAdd(&S[t*4+i], a[i]); atomicAdd(&Q[t*4+i], a[4+i]); }
  }
}

// prepx with BN0 finalization fused: per-thread recompute of affine from stats
__global__ __launch_bounds__(256) void prepx_k(const float* x, const float* S, const float* Q,
                                               const float* fs, const float* fb,
                                               const float* gg, const float* bb,
                                               unsigned short* xt){
  int i = blockIdx.x * 256 + threadIdx.x; // N*32 total
  int row = i >> 5; int c = (i & 31) * 4;
  float4 Sv = *(const float4*)(S + c);
  float4 Qv = *(const float4*)(Q + c);
  float4 fs4 = *(const float4*)(fs + c);
  float4 fb4 = *(const float4*)(fb + c);
  float4 gg4 = *(const float4*)(gg + c);
  float4 bb4 = *(const float4*)(bb + c);
  const float invN = 1.0f / N_NODES;
  float mu0 = Sv.x*invN, mu1 = Sv.y*invN, mu2 = Sv.z*invN, mu3 = Sv.w*invN;
  float r0 = rsqrtf(Qv.x*invN - mu0*mu0 + BN_EPS);
  float r1 = rsqrtf(Qv.y*invN - mu1*mu1 + BN_EPS);
  float r2 = rsqrtf(Qv.z*invN - mu2*mu2 + BN_EPS);
  float r3 = rsqrtf(Qv.w*invN - mu3*mu3 + BN_EPS);
  float a0 = gg4.x*r0*fs4.x, b0 = gg4.x*r0*(fb4.x - mu0) + bb4.x;
  float a1 = gg4.y*r1*fs4.y, b1 = gg4.y*r1*(fb4.y - mu1) + bb4.y;
  float a2 = gg4.z*r2*fs4.z, b2 = gg4.z*r2*(fb4.z - mu2) + bb4.z;
  float a3 = gg4.w*r3*fs4.w, b3 = gg4.w*r3*(fb4.w - mu3) + bb4.w;
  float4 xv = *(const float4*)(x + (size_t)row * D_IN + c);
  uint2 o;
  o.x = pack2(a0 * xv.x + b0, a1 * xv.y + b1);
  o.y = pack2(a2 * xv.z + b2, a3 * xv.w + b3);
  *(uint2*)(xt + (size_t)row * D_IN + c) = o;
}

__global__ void transpose2_k(const float* W1, const float* W2,
                             unsigned short* W1t, unsigned short* W2t){
  int i = blockIdx.x * 256 + threadIdx.x;
  if (i < D_IN * H_DIM){
    int r = i / H_DIM, c = i % H_DIM;
    W1t[c * D_IN + r] = f2bf(W1[i]);
  }
  if (i < H_DIM * H_DIM){
    int r = i / H_DIM, c = i % H_DIM;
    W2t[c * H_DIM + r] = f2bf(W2[i]);
  }
}

// ---------------- bf16 MFMA GEMM: 64x256 tile, C slice-major [8][N][32] ----------------
template<int K>
__global__ __launch_bounds__(256) void gemm_k(const unsigned short* A, const unsigned short* Bt,
                                              unsigned short* C, int M){
  __shared__ __align__(16) short smem[16896];
  short* As = smem;               // [64][40]
  short* Bs = smem + 64 * 40;     // [256][40]
  int t = threadIdx.x;
  int m0 = blockIdx.x * 64;
  int lane = t & 63;
  int w = t >> 6;                 // wave -> col block w*64
  int fr = lane & 15, quad = lane >> 4;
  v4f acc[4][4] = {};
  int sr = t >> 2;                // 0..63
  int sk = (t & 3) << 3;          // 0,8,16,24
  for (int k0 = 0; k0 < K; k0 += 32){
    __syncthreads();
    uint4 av = {0,0,0,0};
    int arow = m0 + sr;
    if (arow < M) av = *(const uint4*)(A + (size_t)arow * K + k0 + sk);
    *(uint4*)(&As[sr * 40 + sk]) = av;
    #pragma unroll
    for (int j = 0; j < 4; ++j){
      int brow = sr + 64 * j;
      uint4 bv = *(const uint4*)(Bt + (size_t)brow * K + k0 + sk);
      *(uint4*)(&Bs[brow * 40 + sk]) = bv;
    }
    __syncthreads();
    v8s af[4], bf[4];
    #pragma unroll
    for (int mi = 0; mi < 4; ++mi)
      af[mi] = *(const v8s*)(&As[(mi * 16 + fr) * 40 + quad * 8]);
    #pragma unroll
    for (int ni = 0; ni < 4; ++ni)
      bf[ni] = *(const v8s*)(&Bs[(w * 64 + ni * 16 + fr) * 40 + quad * 8]);
    #pragma unroll
    for (int mi = 0; mi < 4; ++mi)
      #pragma unroll
      for (int ni = 0; ni < 4; ++ni)
        acc[mi][ni] = __builtin_amdgcn_mfma_f32_16x16x32_bf16(af[mi], bf[ni], acc[mi][ni], 0, 0, 0);
  }
  __syncthreads();
  short* Cs = smem; // [64][264]
  #pragma unroll
  for (int mi = 0; mi < 4; ++mi)
    #pragma unroll
    for (int ni = 0; ni < 4; ++ni)
      #pragma unroll
      for (int r = 0; r < 4; ++r){
        int row = mi * 16 + quad * 4 + r;
        int col = w * 64 + ni * 16 + fr;
        Cs[row * 264 + col] = (short)f2bf(acc[mi][ni][r]);
      }
  __syncthreads();
  int orow = t >> 2;
  int grow = m0 + orow;
  if (grow < M){
    #pragma unroll
    for (int j = 0; j < 4; ++j){
      int oc = (t & 3) * 16 + 64 * j;
      v8s v0 = *(const v8s*)(&Cs[orow * 264 + oc]);
      v8s v1 = *(const v8s*)(&Cs[orow * 264 + oc + 8]);
      *(v8s*)(&C[(size_t)(oc >> 5) * SLICE_ELEMS + (size_t)grow * 32 + (oc & 31)]) = v0;
      int oc1 = oc + 8;
      *(v8s*)(&C[(size_t)(oc1 >> 5) * SLICE_ELEMS + (size_t)grow * 32 + (oc1 & 31)]) = v1;
    }
  }
}

// ---------------- edge aggregation: XCD-sliced, LDS-staged descriptors ----------------
// hs: slice-major hlin [8][N][32]; blockIdx.x & 7 = slice; idx = degree rank.
// Block's 32 nodes have a CONTIGUOUS edge window (rank-sequential CSR) -> stage it in LDS
// with coalesced loads; per-group desc reads become ds_reads (no global hop in the chain).
__global__ __launch_bounds__(256) void agg_k(const unsigned short* hs, const int* offsets,
                                             const unsigned* edges, const int* perm,
                                             const float* dinv, const float* bias,
                                             unsigned short* g){
  __shared__ unsigned eds[EDGE_CHUNK];
  int t = threadIdx.x;
  int lane = t & 63;
  int slice = blockIdx.x & 7;
  int l8 = lane & 7;
  int nb = (blockIdx.x >> 3) * 32;
  int idx = nb + (t >> 3);
  int lastn = min(nb + 32, N_NODES);
  int blk0 = offsets[nb];
  int blkN = offsets[lastn];
  int wcnt = min(blkN - blk0, EDGE_CHUNK);
  for (int i = t; i < wcnt; i += 256)
    eds[i] = edges[blk0 + i];
  __syncthreads();
  if (idx >= N_NODES) return;
  int node = perm[idx];
  const unsigned short* hb = hs + (size_t)slice * SLICE_ELEMS;
  float4 bb = *(const float4*)(bias + slice * 32 + l8 * 4);
  float di = dinv[node]; float dii = di * di;
  uint2 sv = *(const uint2*)(hb + (size_t)node * 32 + l8 * 4);
  float a0 = bb.x + dii * bflo(sv.x);
  float a1 = bb.y + dii * bfhi(sv.x);
  float a2 = bb.z + dii * bflo(sv.y);
  float a3 = bb.w + dii * bfhi(sv.y);
  int e  = offsets[idx];
  int e1 = offsets[idx + 1];
  // 8 edges per iteration: descs from LDS, 8 independent gathers in flight
  for (; e + 8 <= e1; e += 8){
    int r = e - blk0;
    unsigned d0, d1, d2, d3, d4, d5, d6, d7;
    if (r + 8 <= EDGE_CHUNK){
      d0 = eds[r];   d1 = eds[r+1]; d2 = eds[r+2]; d3 = eds[r+3];
      d4 = eds[r+4]; d5 = eds[r+5]; d6 = eds[r+6]; d7 = eds[r+7];
    } else {
      d0 = edges[e];   d1 = edges[e+1]; d2 = edges[e+2]; d3 = edges[e+3];
      d4 = edges[e+4]; d5 = edges[e+5]; d6 = edges[e+6]; d7 = edges[e+7];
    }
    uint2 v0 = *(const uint2*)(hb + (size_t)(d0 & 0xffffu) * 32 + l8 * 4);
    uint2 v1 = *(const uint2*)(hb + (size_t)(d1 & 0xffffu) * 32 + l8 * 4);
    uint2 v2 = *(const uint2*)(hb + (size_t)(d2 & 0xffffu) * 32 + l8 * 4);
    uint2 v3 = *(const uint2*)(hb + (size_t)(d3 & 0xffffu) * 32 + l8 * 4);
    uint2 v4 = *(const uint2*)(hb + (size_t)(d4 & 0xffffu) * 32 + l8 * 4);
    uint2 v5 = *(const uint2*)(hb + (size_t)(d5 & 0xffffu) * 32 + l8 * 4);
    uint2 v6 = *(const uint2*)(hb + (size_t)(d6 & 0xffffu) * 32 + l8 * 4);
    uint2 v7 = *(const uint2*)(hb + (size_t)(d7 & 0xffffu) * 32 + l8 * 4);
    float w0 = __uint_as_float(d0 & 0xffff0000u), w1 = __uint_as_float(d1 & 0xffff0000u);
    float w2 = __uint_as_float(d2 & 0xffff0000u), w3 = __uint_as_float(d3 & 0xffff0000u);
    float w4 = __uint_as_float(d4 & 0xffff0000u), w5 = __uint_as_float(d5 & 0xffff0000u);
    float w6 = __uint_as_float(d6 & 0xffff0000u), w7 = __uint_as_float(d7 & 0xffff0000u);
    a0 += w0*bflo(v0.x) + w1*bflo(v1.x) + w2*bflo(v2.x) + w3*bflo(v3.x)
        + w4*bflo(v4.x) + w5*bflo(v5.x) + w6*bflo(v6.x) + w7*bflo(v7.x);
    a1 += w0*bfhi(v0.x) + w1*bfhi(v1.x) + w2*bfhi(v2.x) + w3*bfhi(v3.x)
        + w4*bfhi(v4.x) + w5*bfhi(v5.x) + w6*bfhi(v6.x) + w7*bfhi(v7.x);
    a2 += w0*bflo(v0.y) + w1*bflo(v1.y) + w2*bflo(v2.y) + w3*bflo(v3.y)
        + w4*bflo(v4.y) + w5*bflo(v5.y) + w6*bflo(v6.y) + w7*bflo(v7.y);
    a3 += w0*bfhi(v0.y) + w1*bfhi(v1.y) + w2*bfhi(v2.y) + w3*bfhi(v3.y)
        + w4*bfhi(v4.y) + w5*bfhi(v5.y) + w6*bfhi(v6.y) + w7*bfhi(v7.y);
  }
  // tail
  for (; e < e1; ++e){
    int r = e - blk0;
    unsigned d = (r < EDGE_CHUNK) ? eds[r] : edges[e];
    uint2 v = *(const uint2*)(hb + (size_t)(d & 0xffffu) * 32 + l8 * 4);
    float wg = __uint_as_float(d & 0xffff0000u);
    a0 += wg * bflo(v.x); a1 += wg * bfhi(v.x);
    a2 += wg * bflo(v.y); a3 += wg * bfhi(v.y);
  }
  uint2 o;
  o.x = pack2(fmaxf(a0, 0.f), fmaxf(a1, 0.f));
  o.y = pack2(fmaxf(a2, 0.f), fmaxf(a3, 0.f));
  *(uint2*)(g + (size_t)node * H_DIM + slice * 32 + l8 * 4) = o;
}

// ---------------- column stats over g (bf16 [N,256]) ----------------
__global__ __launch_bounds__(256) void colstats_k(const unsigned short* g, float* S, float* Q){
  int t = threadIdx.x;
  int cl = t & 63, rg = t >> 6;
  int c = cl * 4;
  float s0=0,s1=0,s2=0,s3=0,q0=0,q1=0,q2=0,q3=0;
  for (int row = blockIdx.x * 4 + rg; row < N_NODES; row += gridDim.x * 4){
    uint2 u = *(const uint2*)(g + (size_t)row * H_DIM + c);
    float v0 = bflo(u.x), v1 = bfhi(u.x), v2 = bflo(u.y), v3 = bfhi(u.y);
    s0 += v0; s1 += v1; s2 += v2; s3 += v3;
    q0 += v0*v0; q1 += v1*v1; q2 += v2*v2; q3 += v3*v3;
  }
  __shared__ float red[256][8];
  red[t][0]=s0; red[t][1]=s1; red[t][2]=s2; red[t][3]=s3;
  red[t][4]=q0; red[t][5]=q1; red[t][6]=q2; red[t][7]=q3;
  __syncthreads();
  if (t < 64){
    float a[8];
    #pragma unroll
    for (int i = 0; i < 8; ++i) a[i] = red[t][i];
    for (int j = 1; j < 4; ++j)
      #pragma unroll
      for (int i = 0; i < 8; ++i) a[i] += red[t + 64*j][i];
    #pragma unroll
    for (int i = 0; i < 4; ++i){ atomicAdd(&S[t*4+i], a[i]); atomicAdd(&Q[t*4+i], a[4+i]); }
  }
}

// per-thread BN finalize from raw stats (S,Q) for this thread's 4 columns
__device__ __forceinline__ void bn_coeffs(const float* S, const float* Q,
                                          const float* gg, const float* bb, int c,
                                          float4& sc, float4& sh){
  float4 Sv = *(const float4*)(S + c);
  float4 Qv = *(const float4*)(Q + c);
  float4 g4 = *(const float4*)(gg + c);
  float4 b4 = *(const float4*)(bb + c);
  const float invN = 1.0f / N_NODES;
  float mu0 = Sv.x*invN, mu1 = Sv.y*invN, mu2 = Sv.z*invN, mu3 = Sv.w*invN;
  sc.x = g4.x * rsqrtf(Qv.x*invN - mu0*mu0 + BN_EPS);
  sc.y = g4.y * rsqrtf(Qv.y*invN - mu1*mu1 + BN_EPS);
  sc.z = g4.z * rsqrtf(Qv.z*invN - mu2*mu2 + BN_EPS);
  sc.w = g4.w * rsqrtf(Qv.w*invN - mu3*mu3 + BN_EPS);
  sh.x = b4.x - sc.x * mu0; sh.y = b4.y - sc.y * mu1;
  sh.z = b4.z - sc.z * mu2; sh.w = b4.w - sc.w * mu3;
}

// ---------------- BN + LN apply (layer 1): h1 = LN(BN(g)) ----------------
__global__ __launch_bounds__(256) void apply1_k(const unsigned short* g, const float* S, const float* Q,
                                                const float* bng, const float* bnb,
                                                const float* lng, const float* lnb, unsigned short* h1){
  int lane = threadIdx.x & 63;
  int row = blockIdx.x * 4 + (threadIdx.x >> 6);
  if (row >= N_NODES) return;
  int c = lane * 4;
  float4 s4, h4;
  bn_coeffs(S, Q, bng, bnb, c, s4, h4);
  uint2 u = *(const uint2*)(g + (size_t)row * H_DIM + c);
  float v0 = s4.x * bflo(u.x) + h4.x;
  float v1 = s4.y * bfhi(u.x) + h4.y;
  float v2 = s4.z * bflo(u.y) + h4.z;
  float v3 = s4.w * bfhi(u.y) + h4.w;
  float sum = wred(v0 + v1 + v2 + v3);
  float sq  = wred(v0*v0 + v1*v1 + v2*v2 + v3*v3);
  float mu = sum * (1.0f / H_DIM);
  float var = sq * (1.0f / H_DIM) - mu * mu;
  float rs = rsqrtf(var + LN_EPS);
  float4 g4 = *(const float4*)(lng + c);
  float4 b4 = *(const float4*)(lnb + c);
  float y0 = g4.x * (v0 - mu) * rs + b4.x;
  float y1 = g4.y * (v1 - mu) * rs + b4.y;
  float y2 = g4.z * (v2 - mu) * rs + b4.z;
  float y3 = g4.w * (v3 - mu) * rs + b4.w;
  uint2 o; o.x = pack2(y0, y1); o.y = pack2(y2, y3);
  *(uint2*)(h1 + (size_t)row * H_DIM + c) = o;
}

// ---------------- layer 2 apply + residual + output GEMM ----------------
__global__ __launch_bounds__(256) void apply2_k(const unsigned short* g, const float* S, const float* Q,
                                                const float* bng, const float* bnb,
                                                const float* lng, const float* lnb,
                                                const unsigned short* h1, const float* Wout,
                                                const float* bout, float* out){
  int lane = threadIdx.x & 63;
  int row = blockIdx.x * 4 + (threadIdx.x >> 6);
  if (row >= N_NODES) return;
  int c = lane * 4;
  float4 s4, h4;
  bn_coeffs(S, Q, bng, bnb, c, s4, h4);
  uint2 u = *(const uint2*)(g + (size_t)row * H_DIM + c);
  float v0 = s4.x * bflo(u.x) + h4.x;
  float v1 = s4.y * bfhi(u.x) + h4.y;
  float v2 = s4.z * bflo(u.y) + h4.z;
  float v3 = s4.w * bfhi(u.y) + h4.w;
  float sum = wred(v0 + v1 + v2 + v3);
  float sq  = wred(v0*v0 + v1*v1 + v2*v2 + v3*v3);
  float mu = sum * (1.0f / H_DIM);
  float var = sq * (1.0f / H_DIM) - mu * mu;
  float rs = rsqrtf(var + LN_EPS);
  float4 g4 = *(const float4*)(lng + c);
  float4 b4 = *(const float4*)(lnb + c);
  uint2 hr = *(const uint2*)(h1 + (size_t)row * H_DIM + c);
  float y0 = g4.x * (v0 - mu) * rs + b4.x + bflo(hr.x);
  float y1 = g4.y * (v1 - mu) * rs + b4.y + bfhi(hr.x);
  float y2 = g4.z * (v2 - mu) * rs + b4.z + bflo(hr.y);
  float y3 = g4.w * (v3 - mu) * rs + b4.w + bfhi(hr.y);
  float4 w0 = *(const float4*)(Wout + c * 2);
  float4 w1 = *(const float4*)(Wout + c * 2 + 4);
  float o0 = y0 * w0.x + y1 * w0.z + y2 * w1.x + y3 * w1.z;
  float o1 = y0 * w0.y + y1 * w0.w + y2 * w1.y + y3 * w1.w;
  o0 = wred(o0); o1 = wred(o1);
  if (lane == 0){
    out[(size_t)row * 2 + 0] = o0 + bout[0];
    out[(size_t)row * 2 + 1] = o1 + bout[1];
  }
}

extern "C" void kernel_launch(void* const* d_in, const int* in_sizes, int n_in,
                              void* d_out, int out_size, void* d_ws, size_t ws_size,
                              hipStream_t stream) {
  const float* x    = (const float*)d_in[0];
  const int*   ei   = (const int*)d_in[1];
  const float* fs   = (const float*)d_in[2];
  const float* fb   = (const float*)d_in[3];
  const float* bn0g = (const float*)d_in[4];
  const float* bn0b = (const float*)d_in[5];
  const float* W1   = (const float*)d_in[6];
  const float* b1   = (const float*)d_in[7];
  const float* bn1g = (const float*)d_in[8];
  const float* bn1b = (const float*)d_in[9];
  const float* ln1g = (const float*)d_in[10];
  const float* ln1b = (const float*)d_in[11];
  const float* W2   = (const float*)d_in[12];
  const float* b2   = (const float*)d_in[13];
  const float* bn2g = (const float*)d_in[14];
  const float* bn2b = (const float*)d_in[15];
  const float* ln2g = (const float*)d_in[16];
  const float* ln2b = (const float*)d_in[17];
  const float* Wout = (const float*)d_in[18];
  const float* bout = (const float*)d_in[19];
  float* out = (float*)d_out;

  char* w = (char*)d_ws;
  // zeroed region (one memset): cnt + stat sums + degree histogram
  int*   cnt   = (int*)(w + 0);            // 200000 B
  float* bn0S  = (float*)(w + 200000);     // 512
  float* bn0Q  = (float*)(w + 200512);     // 512
  float* S1    = (float*)(w + 201024);     // 1024
  float* Q1    = (float*)(w + 202048);     // 1024
  float* S2    = (float*)(w + 203072);     // 1024
  float* Q2    = (float*)(w + 204096);     // 1024 -> 205120
  int*   dhist = (int*)(w + 205120);       // 256  -> 205376
  const size_t ZERO_BYTES = 205376;
  int*   bsum  = (int*)(w + 205376);       // 1024 -> 206400 (fully written by blocksum_k)
  int*   dcur  = (int*)(w + 206400);       // 256  -> 206656
  int*   bpre  = (int*)(w + 206656);       // 1024 -> 207680
  float* dinv  = (float*)(w + 207680);     // 200000 -> 407680
  int*   offs  = (int*)(w + 407680);       // 200004 -> pad 607744
  int*   curs  = (int*)(w + 607744);       // 200000 -> 807744
  int*   perm  = (int*)(w + 807744);       // 200000 -> 1007744
  int*   rank  = (int*)(w + 1007744);      // 200000 -> 1207744
  unsigned* edges = (unsigned*)(w + 1207744); // 3200000 -> 4407744 (16B aligned)
  unsigned short* xt   = (unsigned short*)(w + 4407744);   // 12.8 MB -> 17207744
  unsigned short* W1t  = (unsigned short*)(w + 17207744);  // 64 KB  -> 17273280
  unsigned short* W2t  = (unsigned short*)(w + 17273280);  // 128 KB -> 17404352
  unsigned short* hlin = (unsigned short*)(w + 17404352);  // 25.6 MB (slice-major [8][N][32])
  unsigned short* gbuf = (unsigned short*)(w + 43004352);  // 25.6 MB (row-major)
  unsigned short* h1   = (unsigned short*)(w + 68604352);  // 25.6 MB -> 94204352

  (void)in_sizes; (void)n_in; (void)out_size; (void)ws_size;

  hipMemsetAsync(d_ws, 0, ZERO_BYTES, stream);

  // graph preprocessing: degree -> degree-sort relabeling -> sorted CSR
  deg_k<<<(N_EDGES + 255) / 256, 256, 0, stream>>>(ei, cnt);
  hist_k<<<NBLK_SCAN, 256, 0, stream>>>(cnt, dhist);
  dscan_k<<<1, 64, 0, stream>>>(dhist, dcur);
  dperm_k<<<NBLK_SCAN, 256, 0, stream>>>(cnt, dcur, perm, rank);
  blocksum_k<<<NBLK_SCAN, 256, 0, stream>>>(cnt, perm, bsum);
  bscan_k<<<1, 256, 0, stream>>>(bsum, bpre, offs);
  cscan_k<<<NBLK_SCAN, 256, 0, stream>>>(cnt, perm, bpre, offs, curs, dinv);
  csr_k<<<(N_EDGES + 255) / 256, 256, 0, stream>>>(ei, dinv, rank, curs, edges);

  // input transform + BN0 folded into affine, cast to bf16 (finalize fused in prepx)
  bn0stats_k<<<128, 256, 0, stream>>>(x, fs, fb, bn0S, bn0Q);
  prepx_k<<<(N_NODES * 32) / 256, 256, 0, stream>>>(x, bn0S, bn0Q, fs, fb, bn0g, bn0b, xt);

  // weight transposes (bf16, K-inner), merged
  transpose2_k<<<(H_DIM * H_DIM + 255) / 256, 256, 0, stream>>>(W1, W2, W1t, W2t);

  int ggrid = (N_NODES + 63) / 64;
  int agg_blocks = ((N_NODES + 31) / 32) * 8;

  // ---- layer 1 ----
  gemm_k<D_IN><<<ggrid, 256, 0, stream>>>(xt, W1t, hlin, N_NODES);
  agg_k<<<agg_blocks, 256, 0, stream>>>(hlin, offs, edges, perm, dinv, b1, gbuf);
  colstats_k<<<104, 256, 0, stream>>>(gbuf, S1, Q1);
  apply1_k<<<(N_NODES + 3) / 4, 256, 0, stream>>>(gbuf, S1, Q1, bn1g, bn1b, ln1g, ln1b, h1);

  // ---- layer 2 ----
  gemm_k<H_DIM><<<ggrid, 256, 0, stream>>>(h1, W2t, hlin, N_NODES);
  agg_k<<<agg_blocks, 256, 0, stream>>>(hlin, offs, edges, perm, dinv, b2, gbuf);
  colstats_k<<<104, 256, 0, stream>>>(gbuf, S2, Q2);
  apply2_k<<<(N_NODES + 3) / 4, 256, 0, stream>>>(gbuf, S2, Q2, bn2g, bn2b, ln2g, ln2b, h1, Wout, bout, out);
}